// Round 1
// baseline (1802.437 us; speedup 1.0000x reference)
//
#include <hip/hip_runtime.h>

typedef __attribute__((ext_vector_type(8))) short short8;
typedef __attribute__((ext_vector_type(4))) float floatx4;
typedef unsigned short ushort_t;

static __device__ __forceinline__ ushort_t f2bf(float f) {
  union { float f; unsigned u; } v; v.f = f;
  unsigned r = v.u + 0x7fffu + ((v.u >> 16) & 1u);
  return (ushort_t)(r >> 16);
}
static __device__ __forceinline__ float bf2f(ushort_t s) {
  union { unsigned u; float f; } v; v.u = ((unsigned)s) << 16; return v.f;
}

// ---------------- fp32 -> bf16 conversion ----------------
__global__ void conv_kernel(const float* __restrict__ src, ushort_t* __restrict__ dst, int n) {
  int i = (blockIdx.x * blockDim.x + threadIdx.x) * 4;
  if (i >= n) return;
  float4 f = *(const float4*)(src + i);
  ushort4 u;
  u.x = f2bf(f.x); u.y = f2bf(f.y); u.z = f2bf(f.z); u.w = f2bf(f.w);
  *(ushort4*)(dst + i) = u;
}

// ---------------- bias concat [bq | 0 | bv] ----------------
__global__ void biascat_kernel(const float* __restrict__ bq, const float* __restrict__ bv,
                               float* __restrict__ bcat) {
  int i = blockIdx.x * blockDim.x + threadIdx.x; // 0..3071
  float v = 0.f;
  if (i < 1024) v = bq[i];
  else if (i >= 2048) v = bv[i - 2048];
  bcat[i] = v;
}

// ---------------- generic NT GEMM: C[m,n] = sum_k A[m,k]*B[n,k] + bias[n] ----------------
// A: [M,K] bf16 row-major, B: [N,K] bf16 row-major. Writes fp32 (Cf) or bf16 (Cb).
__global__ __launch_bounds__(256) void gemm_bt(
    const ushort_t* __restrict__ A, const ushort_t* __restrict__ Bm,
    const float* __restrict__ bias, float* __restrict__ Cf,
    ushort_t* __restrict__ Cb, int M, int N, int K)
{
  __shared__ ushort_t As[128 * 72];
  __shared__ ushort_t Bs[128 * 72];
  const int tid = threadIdx.x;
  const int wave = tid >> 6, lane = tid & 63;
  const int wm = wave >> 1, wn = wave & 1;
  const int lane15 = lane & 15, quad = lane >> 4;
  const int m0 = blockIdx.y * 128, n0 = blockIdx.x * 128;
  const int lrow = tid >> 3;
  const int lcol = (tid & 7) * 8;

  floatx4 acc[4][4];
#pragma unroll
  for (int a = 0; a < 4; ++a)
#pragma unroll
    for (int b = 0; b < 4; ++b) acc[a][b] = (floatx4){0.f, 0.f, 0.f, 0.f};

  for (int k0 = 0; k0 < K; k0 += 64) {
    __syncthreads();
#pragma unroll
    for (int l = 0; l < 4; ++l) {
      int row = l * 32 + lrow;
      *(short8*)(&As[row * 72 + lcol]) = *(const short8*)(A + (size_t)(m0 + row) * K + k0 + lcol);
      *(short8*)(&Bs[row * 72 + lcol]) = *(const short8*)(Bm + (size_t)(n0 + row) * K + k0 + lcol);
    }
    __syncthreads();
#pragma unroll
    for (int ks = 0; ks < 64; ks += 32) {
      short8 af[4], bf[4];
#pragma unroll
      for (int mi = 0; mi < 4; ++mi)
        af[mi] = *(const short8*)(&As[(wm * 64 + mi * 16 + lane15) * 72 + ks + quad * 8]);
#pragma unroll
      for (int ni = 0; ni < 4; ++ni)
        bf[ni] = *(const short8*)(&Bs[(wn * 64 + ni * 16 + lane15) * 72 + ks + quad * 8]);
#pragma unroll
      for (int mi = 0; mi < 4; ++mi)
#pragma unroll
        for (int ni = 0; ni < 4; ++ni)
          acc[mi][ni] = __builtin_amdgcn_mfma_f32_16x16x32_bf16(af[mi], bf[ni], acc[mi][ni], 0, 0, 0);
    }
  }

#pragma unroll
  for (int mi = 0; mi < 4; ++mi) {
#pragma unroll
    for (int ni = 0; ni < 4; ++ni) {
      const int col = n0 + wn * 64 + ni * 16 + lane15;
      const float bv = bias ? bias[col] : 0.f;
#pragma unroll
      for (int v = 0; v < 4; ++v) {
        const int row = m0 + wm * 64 + mi * 16 + quad * 4 + v;
        const float val = acc[mi][ni][v] + bv;
        if (Cf) Cf[(size_t)row * N + col] = val;
        else    Cb[(size_t)row * N + col] = f2bf(val);
      }
    }
  }
}

// ---------------- rotary in-place on bf16 QKV [4096, 3072] (colbase 0=Q, 1024=K) ------------
__global__ void rotary_kernel(ushort_t* __restrict__ qkv, const float* __restrict__ inv_freq,
                              int colbase) {
  int tid = blockIdx.x * blockDim.x + threadIdx.x; // 0 .. 2*2048*16*32-1
  int f = tid & 31;
  int h = (tid >> 5) & 15;
  int s = (tid >> 9) & 2047;
  int b = tid >> 20;
  size_t idx = (size_t)(b * 2048 + s) * 3072 + colbase + h * 64 + 2 * f;
  float ang = (float)s * inv_freq[f];
  float sn, cs;
  sincosf(ang, &sn, &cs);
  float a = bf2f(qkv[idx]);
  float bb = bf2f(qkv[idx + 1]);
  qkv[idx]     = f2bf(a * cs - bb * sn);
  qkv[idx + 1] = f2bf(a * sn + bb * cs);
}

// ---------------- QK^T with analytic causal mask -> fp32 qk output ----------------
__global__ __launch_bounds__(256) void qk_kernel(
    const ushort_t* __restrict__ QKV, float* __restrict__ qk_out)
{
  __shared__ ushort_t Qs[128 * 72];
  __shared__ ushort_t Ks[128 * 72];
  const int tid = threadIdx.x;
  const int wave = tid >> 6, lane = tid & 63;
  const int wm = wave >> 1, wn = wave & 1;
  const int lane15 = lane & 15, quad = lane >> 4;
  const int bh = blockIdx.z;
  const int b = bh >> 4, h = bh & 15;
  const int i0 = blockIdx.y * 128, j0 = blockIdx.x * 128;
  const ushort_t* Qb = QKV + (size_t)b * 2048 * 3072 + h * 64;
  const ushort_t* Kb = QKV + (size_t)b * 2048 * 3072 + 1024 + h * 64;
  const int lrow = tid >> 3;
  const int lcol = (tid & 7) * 8;
#pragma unroll
  for (int l = 0; l < 4; ++l) {
    int r = l * 32 + lrow;
    *(short8*)(&Qs[r * 72 + lcol]) = *(const short8*)(Qb + (size_t)(i0 + r) * 3072 + lcol);
    *(short8*)(&Ks[r * 72 + lcol]) = *(const short8*)(Kb + (size_t)(j0 + r) * 3072 + lcol);
  }
  __syncthreads();

  floatx4 acc[4][4];
#pragma unroll
  for (int a = 0; a < 4; ++a)
#pragma unroll
    for (int bb = 0; bb < 4; ++bb) acc[a][bb] = (floatx4){0.f, 0.f, 0.f, 0.f};

#pragma unroll
  for (int ks = 0; ks < 64; ks += 32) {
    short8 af[4], bf[4];
#pragma unroll
    for (int mi = 0; mi < 4; ++mi)
      af[mi] = *(const short8*)(&Qs[(wm * 64 + mi * 16 + lane15) * 72 + ks + quad * 8]);
#pragma unroll
    for (int ni = 0; ni < 4; ++ni)
      bf[ni] = *(const short8*)(&Ks[(wn * 64 + ni * 16 + lane15) * 72 + ks + quad * 8]);
#pragma unroll
    for (int mi = 0; mi < 4; ++mi)
#pragma unroll
      for (int ni = 0; ni < 4; ++ni)
        acc[mi][ni] = __builtin_amdgcn_mfma_f32_16x16x32_bf16(af[mi], bf[ni], acc[mi][ni], 0, 0, 0);
  }

  float* out = qk_out + (size_t)bh * 2048 * 2048;
#pragma unroll
  for (int mi = 0; mi < 4; ++mi) {
#pragma unroll
    for (int ni = 0; ni < 4; ++ni) {
      const int j = j0 + wn * 64 + ni * 16 + lane15;
#pragma unroll
      for (int v = 0; v < 4; ++v) {
        const int i = i0 + wm * 64 + mi * 16 + quad * 4 + v;
        float val = acc[mi][ni][v] * 0.125f + ((j <= i) ? 0.f : -1e9f);
        out[(size_t)i * 2048 + j] = val;
      }
    }
  }
}

// ---------------- per-row softmax + P*V (one wave per row) ----------------
__global__ __launch_bounds__(256) void softmax_pv_kernel(
    const float* __restrict__ qk, const ushort_t* __restrict__ QKV,
    ushort_t* __restrict__ AO)
{
  __shared__ float pbuf[4][64];
  const int wave = threadIdx.x >> 6, lane = threadIdx.x & 63;
  const int r = blockIdx.x * 4 + wave;      // 0 .. 65535
  const int b = r >> 15;
  const int h = (r >> 11) & 15;
  const int i = r & 2047;
  const float* row = qk + ((size_t)((b * 16 + h) * 2048) + i) * 2048;
  const int L = i + 1;

  float m = -3.4e38f;
  for (int j = lane; j < L; j += 64) m = fmaxf(m, row[j]);
#pragma unroll
  for (int off = 32; off >= 1; off >>= 1) m = fmaxf(m, __shfl_xor(m, off));

  const ushort_t* vbase = QKV + (size_t)(b * 2048) * 3072 + 2048 + h * 64 + lane;
  float accv = 0.f, ssum = 0.f;
  for (int jb = 0; jb < L; jb += 64) {
    int j = jb + lane;
    float p = (j < L) ? __expf(row[j] - m) : 0.f;
    ssum += p;
    pbuf[wave][lane] = p;
    int lim = min(64, L - jb);
    for (int jj = 0; jj < lim; ++jj) {
      accv += pbuf[wave][jj] * bf2f(vbase[(size_t)(jb + jj) * 3072]);
    }
  }
#pragma unroll
  for (int off = 32; off >= 1; off >>= 1) ssum += __shfl_xor(ssum, off);

  AO[(size_t)(b * 2048 + i) * 1024 + h * 64 + lane] = f2bf(accv / ssum);
}

extern "C" void kernel_launch(void* const* d_in, const int* in_sizes, int n_in,
                              void* d_out, int out_size, void* d_ws, size_t ws_size,
                              hipStream_t stream) {
  const float* x  = (const float*)d_in[0];
  // d_in[1] = mask — not read; causal mask applied analytically
  const float* Wq = (const float*)d_in[2];
  const float* bq = (const float*)d_in[3];
  const float* Wk = (const float*)d_in[4];
  const float* Wv = (const float*)d_in[5];
  const float* bv = (const float*)d_in[6];
  const float* Wo = (const float*)d_in[7];
  const float* bo = (const float*)d_in[8];
  const float* inv_freq = (const float*)d_in[9];

  char* ws = (char*)d_ws;
  ushort_t* xb   = (ushort_t*)(ws);                     // [4096,1024] bf16, 8 MB
  ushort_t* wb   = (ushort_t*)(ws + ((size_t)8  << 20)); // [4096,1024] bf16 (Wq,Wk,Wv,Wo), 8 MB
  float*    bcat = (float*)  (ws + ((size_t)16 << 20)); // 3072 fp32
  ushort_t* qkv  = (ushort_t*)(ws + ((size_t)17 << 20)); // [4096,3072] bf16, 24 MB
  ushort_t* aob  = (ushort_t*)(ws + ((size_t)41 << 20)); // [4096,1024] bf16, 8 MB

  float* out0  = (float*)d_out;
  float* qkout = out0 + 4194304;

  conv_kernel<<<4096, 256, 0, stream>>>(x, xb, 4194304);
  conv_kernel<<<1024, 256, 0, stream>>>(Wq, wb,           1048576);
  conv_kernel<<<1024, 256, 0, stream>>>(Wk, wb + 1048576, 1048576);
  conv_kernel<<<1024, 256, 0, stream>>>(Wv, wb + 2097152, 1048576);
  conv_kernel<<<1024, 256, 0, stream>>>(Wo, wb + 3145728, 1048576);
  biascat_kernel<<<12, 256, 0, stream>>>(bq, bv, bcat);

  // QKV projection: [4096,1024] x [3072,1024]^T -> bf16 [4096,3072]
  gemm_bt<<<dim3(24, 32), 256, 0, stream>>>(xb, wb, bcat, nullptr, qkv, 4096, 3072, 1024);

  rotary_kernel<<<8192, 256, 0, stream>>>(qkv, inv_freq, 0);     // Q
  rotary_kernel<<<8192, 256, 0, stream>>>(qkv, inv_freq, 1024);  // K

  // QK^T + mask -> d_out qk region (fp32)
  qk_kernel<<<dim3(16, 16, 32), 256, 0, stream>>>(qkv, qkout);

  // softmax + PV -> bf16 attention output [4096,1024]
  softmax_pv_kernel<<<16384, 256, 0, stream>>>(qkout, qkv, aob);

  // output projection -> fp32 out region
  gemm_bt<<<dim3(8, 32), 256, 0, stream>>>(aob, wb + 3145728, bo, out0, nullptr, 4096, 1024, 1024);
}

// Round 2
// 1003.381 us; speedup vs baseline: 1.7964x; 1.7964x over previous
//
#include <hip/hip_runtime.h>

typedef __attribute__((ext_vector_type(8))) short short8;
typedef __attribute__((ext_vector_type(4))) float floatx4;
typedef unsigned short ushort_t;

static __device__ __forceinline__ ushort_t f2bf(float f) {
  union { float f; unsigned u; } v; v.f = f;
  unsigned r = v.u + 0x7fffu + ((v.u >> 16) & 1u);
  return (ushort_t)(r >> 16);
}
static __device__ __forceinline__ float bf2f(ushort_t s) {
  union { unsigned u; float f; } v; v.u = ((unsigned)s) << 16; return v.f;
}

// ---------------- fp32 -> bf16 conversion ----------------
__global__ void conv_kernel(const float* __restrict__ src, ushort_t* __restrict__ dst, int n) {
  int i = (blockIdx.x * blockDim.x + threadIdx.x) * 4;
  if (i >= n) return;
  float4 f = *(const float4*)(src + i);
  ushort4 u;
  u.x = f2bf(f.x); u.y = f2bf(f.y); u.z = f2bf(f.z); u.w = f2bf(f.w);
  *(ushort4*)(dst + i) = u;
}

// ---------------- bias concat [bq | 0 | bv] ----------------
__global__ void biascat_kernel(const float* __restrict__ bq, const float* __restrict__ bv,
                               float* __restrict__ bcat) {
  int i = blockIdx.x * blockDim.x + threadIdx.x; // 0..3071
  float v = 0.f;
  if (i < 1024) v = bq[i];
  else if (i >= 2048) v = bv[i - 2048];
  bcat[i] = v;
}

// ---------------- generic NT GEMM: C[m,n] = sum_k A[m,k]*B[n,k] + bias[n] ----------------
__global__ __launch_bounds__(256) void gemm_bt(
    const ushort_t* __restrict__ A, const ushort_t* __restrict__ Bm,
    const float* __restrict__ bias, float* __restrict__ Cf,
    ushort_t* __restrict__ Cb, int M, int N, int K)
{
  __shared__ ushort_t As[128 * 72];
  __shared__ ushort_t Bs[128 * 72];
  const int tid = threadIdx.x;
  const int wave = tid >> 6, lane = tid & 63;
  const int wm = wave >> 1, wn = wave & 1;
  const int lane15 = lane & 15, quad = lane >> 4;
  const int m0 = blockIdx.y * 128, n0 = blockIdx.x * 128;
  const int lrow = tid >> 3;
  const int lcol = (tid & 7) * 8;

  floatx4 acc[4][4];
#pragma unroll
  for (int a = 0; a < 4; ++a)
#pragma unroll
    for (int b = 0; b < 4; ++b) acc[a][b] = (floatx4){0.f, 0.f, 0.f, 0.f};

  for (int k0 = 0; k0 < K; k0 += 64) {
    __syncthreads();
#pragma unroll
    for (int l = 0; l < 4; ++l) {
      int row = l * 32 + lrow;
      *(short8*)(&As[row * 72 + lcol]) = *(const short8*)(A + (size_t)(m0 + row) * K + k0 + lcol);
      *(short8*)(&Bs[row * 72 + lcol]) = *(const short8*)(Bm + (size_t)(n0 + row) * K + k0 + lcol);
    }
    __syncthreads();
#pragma unroll
    for (int ks = 0; ks < 64; ks += 32) {
      short8 af[4], bf[4];
#pragma unroll
      for (int mi = 0; mi < 4; ++mi)
        af[mi] = *(const short8*)(&As[(wm * 64 + mi * 16 + lane15) * 72 + ks + quad * 8]);
#pragma unroll
      for (int ni = 0; ni < 4; ++ni)
        bf[ni] = *(const short8*)(&Bs[(wn * 64 + ni * 16 + lane15) * 72 + ks + quad * 8]);
#pragma unroll
      for (int mi = 0; mi < 4; ++mi)
#pragma unroll
        for (int ni = 0; ni < 4; ++ni)
          acc[mi][ni] = __builtin_amdgcn_mfma_f32_16x16x32_bf16(af[mi], bf[ni], acc[mi][ni], 0, 0, 0);
    }
  }

#pragma unroll
  for (int mi = 0; mi < 4; ++mi) {
#pragma unroll
    for (int ni = 0; ni < 4; ++ni) {
      const int col = n0 + wn * 64 + ni * 16 + lane15;
      const float bv = bias ? bias[col] : 0.f;
#pragma unroll
      for (int v = 0; v < 4; ++v) {
        const int row = m0 + wm * 64 + mi * 16 + quad * 4 + v;
        const float val = acc[mi][ni][v] + bv;
        if (Cf) Cf[(size_t)row * N + col] = val;
        else    Cb[(size_t)row * N + col] = f2bf(val);
      }
    }
  }
}

// ---------------- rotary in-place on bf16 QKV [4096, 3072] (colbase 0=Q, 1024=K) ------------
__global__ void rotary_kernel(ushort_t* __restrict__ qkv, const float* __restrict__ inv_freq,
                              int colbase) {
  int tid = blockIdx.x * blockDim.x + threadIdx.x;
  int f = tid & 31;
  int h = (tid >> 5) & 15;
  int s = (tid >> 9) & 2047;
  int b = tid >> 20;
  size_t idx = (size_t)(b * 2048 + s) * 3072 + colbase + h * 64 + 2 * f;
  float ang = (float)s * inv_freq[f];
  float sn, cs;
  sincosf(ang, &sn, &cs);
  float a = bf2f(qkv[idx]);
  float bb = bf2f(qkv[idx + 1]);
  qkv[idx]     = f2bf(a * cs - bb * sn);
  qkv[idx + 1] = f2bf(a * sn + bb * cs);
}

// ---------------- V transpose: VtG[bh][d][s] = V[b,s,h,d]  (bf16) ----------------
__global__ void transpose_v_kernel(const ushort_t* __restrict__ QKV, ushort_t* __restrict__ VtG) {
  int g = blockIdx.x * blockDim.x + threadIdx.x;   // 524288 threads
  int s = g & 2047;
  int dchunk = (g >> 11) & 7;
  int bh = g >> 14;
  int b = bh >> 4, h = bh & 15;
  short8 v = *(const short8*)(QKV + (size_t)(b * 2048 + s) * 3072 + 2048 + h * 64 + dchunk * 8);
  ushort_t* dst = VtG + (size_t)bh * 64 * 2048 + (size_t)dchunk * 8 * 2048 + s;
#pragma unroll
  for (int e = 0; e < 8; ++e) dst[(size_t)e * 2048] = (ushort_t)v[e];
}

// ---------------- fill strictly-upper 128x128 tiles of qk with -1e9 ----------------
__global__ void fill_kernel(float* __restrict__ qk_out) {
  const int tile = blockIdx.x;   // 0..255
  const int it = tile >> 4, jt = tile & 15;
  if (jt <= it) return;
  const float4 val = {-1e9f, -1e9f, -1e9f, -1e9f};
  float* base = qk_out + (size_t)blockIdx.y * 2048 * 2048 + (size_t)it * 128 * 2048 + jt * 128;
#pragma unroll
  for (int l = 0; l < 16; ++l) {
    int idx = l * 256 + threadIdx.x;
    int row = idx >> 5, c4 = (idx & 31) * 4;
    *(float4*)(base + (size_t)row * 2048 + c4) = val;
  }
}

// ---------------- fused flash attention: QK^T -> (store qk) -> online softmax -> PV --------
// grid (16 i-tiles, 32 bh), 256 threads = 4 waves, each wave owns 32 i-rows.
// No __syncthreads: K/V frags come straight from global (L1/L2-resident),
// P round-trips through wave-private LDS to convert C-layout -> A-layout.
__global__ __launch_bounds__(256) void flash_kernel(
    const ushort_t* __restrict__ QKV, const ushort_t* __restrict__ VtG,
    float* __restrict__ qk_out, ushort_t* __restrict__ AO)
{
  __shared__ ushort_t Ps[4][32 * 136];
  const int tid = threadIdx.x;
  const int w = tid >> 6, lane = tid & 63;
  const int lane15 = lane & 15, quad = lane >> 4;
  const int it = 15 - blockIdx.x;          // big tiles dispatched first
  const int bh = blockIdx.y;
  const int b = bh >> 4, h = bh & 15;
  const int i_base = it * 128 + w * 32;    // within-seq row base for this wave
  const size_t srow0 = (size_t)b * 2048;

  // Q fragments (A-layout), held for the whole kernel
  short8 aq[2][2];
#pragma unroll
  for (int mi = 0; mi < 2; ++mi)
#pragma unroll
    for (int kb = 0; kb < 2; ++kb)
      aq[mi][kb] = *(const short8*)(QKV + (srow0 + i_base + mi * 16 + lane15) * 3072
                                    + h * 64 + kb * 32 + quad * 8);

  float mrow[2][4], lrow[2][4];
  floatx4 o[2][4];
#pragma unroll
  for (int mi = 0; mi < 2; ++mi) {
#pragma unroll
    for (int v = 0; v < 4; ++v) { mrow[mi][v] = -3.0e38f; lrow[mi][v] = 0.f; }
#pragma unroll
    for (int nd = 0; nd < 4; ++nd) o[mi][nd] = (floatx4){0.f, 0.f, 0.f, 0.f};
  }

  float* qk_bh = qk_out + (size_t)bh * 2048 * 2048;
  const ushort_t* Vt_bh = VtG + (size_t)bh * 64 * 2048;

  for (int jt = 0; jt <= it; ++jt) {
    const int j0 = jt * 128;

    // ---- S = Q K^T over this 32x128 strip ----
    floatx4 s[2][8];
#pragma unroll
    for (int mi = 0; mi < 2; ++mi)
#pragma unroll
      for (int ni = 0; ni < 8; ++ni) s[mi][ni] = (floatx4){0.f, 0.f, 0.f, 0.f};
#pragma unroll
    for (int ni = 0; ni < 8; ++ni) {
#pragma unroll
      for (int kb = 0; kb < 2; ++kb) {
        short8 bk = *(const short8*)(QKV + (srow0 + j0 + ni * 16 + lane15) * 3072
                                     + 1024 + h * 64 + kb * 32 + quad * 8);
        s[0][ni] = __builtin_amdgcn_mfma_f32_16x16x32_bf16(aq[0][kb], bk, s[0][ni], 0, 0, 0);
        s[1][ni] = __builtin_amdgcn_mfma_f32_16x16x32_bf16(aq[1][kb], bk, s[1][ni], 0, 0, 0);
      }
    }

    // ---- scale + causal mask + store qk + tile row-max ----
    float nm[2][4];
#pragma unroll
    for (int mi = 0; mi < 2; ++mi)
#pragma unroll
      for (int v = 0; v < 4; ++v) nm[mi][v] = mrow[mi][v];
#pragma unroll
    for (int mi = 0; mi < 2; ++mi) {
#pragma unroll
      for (int ni = 0; ni < 8; ++ni) {
        const int j_g = j0 + ni * 16 + lane15;
#pragma unroll
        for (int v = 0; v < 4; ++v) {
          const int i_g = i_base + mi * 16 + quad * 4 + v;
          float val = s[mi][ni][v] * 0.125f + ((j_g <= i_g) ? 0.f : -1e9f);
          s[mi][ni][v] = val;
          qk_bh[(size_t)i_g * 2048 + j_g] = val;
          nm[mi][v] = fmaxf(nm[mi][v], val);
        }
      }
    }
#pragma unroll
    for (int mi = 0; mi < 2; ++mi)
#pragma unroll
      for (int v = 0; v < 4; ++v) {
#pragma unroll
        for (int off = 1; off < 16; off <<= 1)
          nm[mi][v] = fmaxf(nm[mi][v], __shfl_xor(nm[mi][v], off));
      }

    // ---- p = exp(S - m), write to wave-private LDS in A-layout rows ----
    float alpha[2][4], rs[2][4];
#pragma unroll
    for (int mi = 0; mi < 2; ++mi)
#pragma unroll
      for (int v = 0; v < 4; ++v) {
        alpha[mi][v] = __expf(mrow[mi][v] - nm[mi][v]);
        rs[mi][v] = 0.f;
      }
#pragma unroll
    for (int mi = 0; mi < 2; ++mi)
#pragma unroll
      for (int ni = 0; ni < 8; ++ni)
#pragma unroll
        for (int v = 0; v < 4; ++v) {
          float p = __expf(s[mi][ni][v] - nm[mi][v]);
          rs[mi][v] += p;
          Ps[w][(mi * 16 + quad * 4 + v) * 136 + ni * 16 + lane15] = f2bf(p);
        }
#pragma unroll
    for (int mi = 0; mi < 2; ++mi)
#pragma unroll
      for (int v = 0; v < 4; ++v) {
#pragma unroll
        for (int off = 1; off < 16; off <<= 1)
          rs[mi][v] += __shfl_xor(rs[mi][v], off);
        lrow[mi][v] = lrow[mi][v] * alpha[mi][v] + rs[mi][v];
        mrow[mi][v] = nm[mi][v];
      }
#pragma unroll
    for (int mi = 0; mi < 2; ++mi)
#pragma unroll
      for (int nd = 0; nd < 4; ++nd)
#pragma unroll
        for (int v = 0; v < 4; ++v) o[mi][nd][v] *= alpha[mi][v];

    // ---- O += P V  (A-frags from LDS, B-frags from transposed V in global) ----
#pragma unroll
    for (int kb2 = 0; kb2 < 4; ++kb2) {
      short8 ap0 = *(const short8*)&Ps[w][(lane15) * 136 + kb2 * 32 + quad * 8];
      short8 ap1 = *(const short8*)&Ps[w][(16 + lane15) * 136 + kb2 * 32 + quad * 8];
#pragma unroll
      for (int nd = 0; nd < 4; ++nd) {
        short8 bv = *(const short8*)(Vt_bh + (size_t)(nd * 16 + lane15) * 2048
                                     + j0 + kb2 * 32 + quad * 8);
        o[0][nd] = __builtin_amdgcn_mfma_f32_16x16x32_bf16(ap0, bv, o[0][nd], 0, 0, 0);
        o[1][nd] = __builtin_amdgcn_mfma_f32_16x16x32_bf16(ap1, bv, o[1][nd], 0, 0, 0);
      }
    }
  }

  // ---- normalize and write attention output (bf16, [4096, 1024]) ----
#pragma unroll
  for (int mi = 0; mi < 2; ++mi) {
    float inv[4];
#pragma unroll
    for (int v = 0; v < 4; ++v) inv[v] = 1.f / lrow[mi][v];
#pragma unroll
    for (int nd = 0; nd < 4; ++nd)
#pragma unroll
      for (int v = 0; v < 4; ++v) {
        const int i_g = i_base + mi * 16 + quad * 4 + v;
        AO[(srow0 + i_g) * 1024 + h * 64 + nd * 16 + lane15] = f2bf(o[mi][nd][v] * inv[v]);
      }
  }
}

extern "C" void kernel_launch(void* const* d_in, const int* in_sizes, int n_in,
                              void* d_out, int out_size, void* d_ws, size_t ws_size,
                              hipStream_t stream) {
  const float* x  = (const float*)d_in[0];
  // d_in[1] = mask — not read; causal mask applied analytically
  const float* Wq = (const float*)d_in[2];
  const float* bq = (const float*)d_in[3];
  const float* Wk = (const float*)d_in[4];
  const float* Wv = (const float*)d_in[5];
  const float* bv = (const float*)d_in[6];
  const float* Wo = (const float*)d_in[7];
  const float* bo = (const float*)d_in[8];
  const float* inv_freq = (const float*)d_in[9];

  char* ws = (char*)d_ws;
  ushort_t* xb   = (ushort_t*)(ws);                      // [4096,1024] bf16, 8 MB (dead after QKV gemm)
  ushort_t* vtg  = (ushort_t*)(ws);                      // reuses xb region: [32][64][2048] bf16, 8 MB
  ushort_t* wb   = (ushort_t*)(ws + ((size_t)8  << 20)); // Wq|Wk|Wv|Wo bf16, 8 MB
  float*    bcat = (float*)   (ws + ((size_t)16 << 20)); // 3072 fp32
  ushort_t* qkv  = (ushort_t*)(ws + ((size_t)17 << 20)); // [4096,3072] bf16, 24 MB
  ushort_t* aob  = (ushort_t*)(ws + ((size_t)41 << 20)); // [4096,1024] bf16, 8 MB

  float* out0  = (float*)d_out;
  float* qkout = out0 + 4194304;

  conv_kernel<<<4096, 256, 0, stream>>>(x, xb, 4194304);
  conv_kernel<<<1024, 256, 0, stream>>>(Wq, wb,           1048576);
  conv_kernel<<<1024, 256, 0, stream>>>(Wk, wb + 1048576, 1048576);
  conv_kernel<<<1024, 256, 0, stream>>>(Wv, wb + 2097152, 1048576);
  conv_kernel<<<1024, 256, 0, stream>>>(Wo, wb + 3145728, 1048576);
  biascat_kernel<<<12, 256, 0, stream>>>(bq, bv, bcat);

  // QKV projection: [4096,1024] x [3072,1024]^T -> bf16 [4096,3072]
  gemm_bt<<<dim3(24, 32), 256, 0, stream>>>(xb, wb, bcat, nullptr, qkv, 4096, 3072, 1024);

  rotary_kernel<<<8192, 256, 0, stream>>>(qkv, inv_freq, 0);     // Q
  rotary_kernel<<<8192, 256, 0, stream>>>(qkv, inv_freq, 1024);  // K

  // V^T for MFMA B-fragments (xb region is dead now)
  transpose_v_kernel<<<2048, 256, 0, stream>>>(qkv, vtg);

  // masked upper tiles of qk
  fill_kernel<<<dim3(256, 32), 256, 0, stream>>>(qkout);

  // fused attention: writes lower-tri qk tiles + bf16 attention output
  flash_kernel<<<dim3(16, 32), 256, 0, stream>>>(qkv, vtg, qkout, aob);

  // output projection -> fp32 out region
  gemm_bt<<<dim3(8, 32), 256, 0, stream>>>(aob, wb + 3145728, bo, out0, nullptr, 4096, 1024, 1024);
}